// Round 4
// baseline (551.793 us; speedup 1.0000x reference)
//
#include <hip/hip_runtime.h>

// HeavySnow: stamp flakes (0.95 squares, all channels) -> depthwise 5x5
// gaussian blur (zero pad) -> clip [0,1].
// R6: barrier-free register sliding-window blur (R5 structure) with the two
// latency fixes the counters demanded:
//  - 4-deep main-load prefetch (px[4]): consume waits on a load issued 4
//    iterations earlier (~4x slack vs R5's 2-deep) to cover ~500cy HBM latency.
//  - BAND=16 -> 3072 blocks -> 8 resident blocks/CU = 32 waves/CU, pinned by
//    __launch_bounds__(256,8) (requires <=64 VGPR; R5 measured 44, est. +8).
// Mask + wave-edge-halo pipes stay 2-deep (L1/L2-resident, short latency).

#define H_ 1024
#define W_ 1024
#define B_ 16
#define C_ 3
#define NF_ 15728
#define MASK_WORDS_PER_B (H_ * W_ / 32)  // 32768 words (128 KB) per batch

// Gaussian weights: sigma=1.5, K=5, normalized. g = [g0,g1,g2,g1,g0].
#define G0 0.12007838f
#define G1 0.23388076f
#define G2 0.29208172f

__global__ void clear_mask_kernel(uint4* __restrict__ mask, int n4) {
    int i = blockIdx.x * blockDim.x + threadIdx.x;
    if (i < n4) mask[i] = make_uint4(0u, 0u, 0u, 0u);
}

__global__ void stamp_kernel(const int* __restrict__ ys, const int* __restrict__ xs,
                             const int* __restrict__ rs, unsigned int* __restrict__ mask) {
    int t = blockIdx.x * blockDim.x + threadIdx.x;
    if (t >= B_ * NF_) return;
    int b = t / NF_;
    int y0 = ys[t], x0 = xs[t], r = rs[t];
    unsigned int* mb = mask + b * MASK_WORDS_PER_B;
    int xlo = max(x0 - r, 0), xhi = min(x0 + r, W_ - 1);
    int ylo = max(y0 - r, 0), yhi = min(y0 + r, H_ - 1);
    for (int y = ylo; y <= yhi; ++y) {
        int i0 = (y << 10) + xlo;
        int i1 = (y << 10) + xhi;
        int w0 = i0 >> 5, w1 = i1 >> 5;
        unsigned int m0 = ~0u << (i0 & 31);
        unsigned int m1 = ~0u >> (31 - (i1 & 31));
        if (w0 == w1) {
            atomicOr(mb + w0, m0 & m1);
        } else {
            atomicOr(mb + w0, m0);
            atomicOr(mb + w1, m1);
        }
    }
}

constexpr int BAND = 16;           // output rows per block
constexpr int NITER = BAND + 4;    // raw rows consumed per band

__global__ __launch_bounds__(256, 8) void blur_kernel(const float* __restrict__ x,
                                                      const unsigned int* __restrict__ mask,
                                                      float* __restrict__ out) {
    const int plane = blockIdx.z;          // b*C + c
    const int b = plane / C_;
    const float* xp = x + (size_t)plane * (H_ * W_);
    float* op = out + (size_t)plane * (H_ * W_);
    const unsigned int* mb = mask + b * MASK_WORDS_PER_B;

    const int tid = threadIdx.x;
    const int wv = tid >> 6;               // wave id 0..3 -> strip
    const int ln = tid & 63;               // lane -> float4 word in strip
    const int gx4 = (wv << 8) + (ln << 2); // scalar col of this lane's word
    const int y0 = blockIdx.y * BAND;

    const bool isL = (ln == 0), isR = (ln == 63);
    // Halo float2: L lane needs scalars gx4-2,gx4-1; R lane needs gx4+4,gx4+5.
    const int hoff = isL ? gx4 - 2 : gx4 + 4;
    const bool haloOn = (isL || isR) && ((unsigned)hoff < (unsigned)W_);
    const int mwi = gx4 >> 5, mbit = gx4 & 31;
    const int hwi = hoff >> 5, hbit = hoff & 31;

    float4 acc[5];                         // rotating vertical accumulators
    float2 hacc[5];                        // halo accumulators (lanes 0/63)
    #pragma unroll
    for (int s = 0; s < 5; ++s) {
        acc[s] = make_float4(0.f, 0.f, 0.f, 0.f);
        hacc[s] = make_float2(0.f, 0.f);
    }

    float4 px[4];                          // 4-deep main prefetch (HBM stream)
    unsigned int pm[2];                    // 2-deep mask prefetch (L2-resident)
    float2 ph[2];  unsigned int phm[2];    // 2-deep halo prefetch (L1/L2-resident)
    #pragma unroll
    for (int s = 0; s < 4; ++s) px[s] = make_float4(0.f, 0.f, 0.f, 0.f);
    ph[0] = ph[1] = make_float2(0.f, 0.f);
    pm[0] = pm[1] = 0u; phm[0] = phm[1] = 0u;

    auto load_main = [&](int i, float4& vx) {
        int gy = y0 - 2 + i;
        if ((unsigned)gy < (unsigned)H_) {
            vx = *(const float4*)(xp + (gy << 10) + gx4);
        } else {
            vx = make_float4(0.f, 0.f, 0.f, 0.f);
        }
    };
    auto load_aux = [&](int i, unsigned int& vm, float2& vh, unsigned int& vhm) {
        int gy = y0 - 2 + i;
        if ((unsigned)gy < (unsigned)H_) {
            vm = mb[(gy << 5) + mwi];
            if (haloOn) {
                vh = *(const float2*)(xp + (gy << 10) + hoff);
                vhm = mb[(gy << 5) + hwi];
            } else { vh = make_float2(0.f, 0.f); vhm = 0u; }
        } else {
            vm = 0u; vh = make_float2(0.f, 0.f); vhm = 0u;
        }
    };

    load_main(0, px[0]); load_main(1, px[1]);
    load_main(2, px[2]); load_main(3, px[3]);
    load_aux(0, pm[0], ph[0], phm[0]);
    load_aux(1, pm[1], ph[1], phm[1]);

    #pragma unroll
    for (int i = 0; i < NITER; ++i) {
        // consume pending row (raw row gy = y0-2+i), flake substitution
        float4 vr = px[i & 3];
        unsigned int m = pm[i & 1];
        if ((m >> (mbit + 0)) & 1u) vr.x = 0.95f;
        if ((m >> (mbit + 1)) & 1u) vr.y = 0.95f;
        if ((m >> (mbit + 2)) & 1u) vr.z = 0.95f;
        if ((m >> (mbit + 3)) & 1u) vr.w = 0.95f;
        float2 hr = ph[i & 1];
        unsigned int hm = phm[i & 1];
        if ((hm >> (hbit + 0)) & 1u) hr.x = 0.95f;
        if ((hm >> (hbit + 1)) & 1u) hr.y = 0.95f;

        // refill prefetch slots
        if (i + 4 < NITER) load_main(i + 4, px[i & 3]);
        if (i + 2 < NITER) load_aux(i + 2, pm[i & 1], ph[i & 1], phm[i & 1]);

        // vertical accumulation into up to 5 rotating accumulators
        #pragma unroll
        for (int d = -2; d <= 2; ++d) {
            int ti = i - 2 + d;            // target output row index in band
            if (ti < 0 || ti >= BAND) continue;
            const float wk = (d == -2 || d == 2) ? G0 : ((d == -1 || d == 1) ? G1 : G2);
            const int sl = ti % 5;
            acc[sl].x += wk * vr.x; acc[sl].y += wk * vr.y;
            acc[sl].z += wk * vr.z; acc[sl].w += wk * vr.w;
            hacc[sl].x += wk * hr.x; hacc[sl].y += wk * hr.y;
        }

        // finish output row ti = i-4 (all 5 contributions in)
        if (i >= 4) {
            const int ti = i - 4;
            const int sl = ti % 5;
            float4 vb = acc[sl];
            float2 hvb = hacc[sl];
            float az = __shfl_up(vb.z, 1u);    // v[4l-2] from lane l-1
            float aw = __shfl_up(vb.w, 1u);    // v[4l-1]
            float cx = __shfl_down(vb.x, 1u);  // v[4l+4] from lane l+1
            float cy = __shfl_down(vb.y, 1u);  // v[4l+5]
            az = isL ? hvb.x : az;  aw = isL ? hvb.y : aw;
            cx = isR ? hvb.x : cx;  cy = isR ? hvb.y : cy;
            float4 o;
            o.x = G0 * (az + vb.z) + G1 * (aw + vb.y) + G2 * vb.x;
            o.y = G0 * (aw + vb.w) + G1 * (vb.x + vb.z) + G2 * vb.y;
            o.z = G0 * (vb.x + cx) + G1 * (vb.y + vb.w) + G2 * vb.z;
            o.w = G0 * (vb.y + cy) + G1 * (vb.z + cx) + G2 * vb.w;
            o.x = fminf(fmaxf(o.x, 0.0f), 1.0f);
            o.y = fminf(fmaxf(o.y, 0.0f), 1.0f);
            o.z = fminf(fmaxf(o.z, 0.0f), 1.0f);
            o.w = fminf(fmaxf(o.w, 0.0f), 1.0f);
            *(float4*)(op + ((y0 + ti) << 10) + gx4) = o;
            acc[sl] = make_float4(0.f, 0.f, 0.f, 0.f);
            hacc[sl] = make_float2(0.f, 0.f);
        }
    }
}

extern "C" void kernel_launch(void* const* d_in, const int* in_sizes, int n_in,
                              void* d_out, int out_size, void* d_ws, size_t ws_size,
                              hipStream_t stream) {
    const float* x  = (const float*)d_in[0];
    const int*   ys = (const int*)d_in[1];
    const int*   xs = (const int*)d_in[2];
    const int*   rs = (const int*)d_in[3];
    float* out = (float*)d_out;
    unsigned int* mask = (unsigned int*)d_ws;  // 16 * 32768 words = 2 MB

    int n4 = B_ * MASK_WORDS_PER_B / 4;
    clear_mask_kernel<<<dim3((n4 + 255) / 256), dim3(256), 0, stream>>>((uint4*)mask, n4);

    int nst = B_ * NF_;
    stamp_kernel<<<dim3((nst + 255) / 256), dim3(256), 0, stream>>>(ys, xs, rs, mask);

    dim3 grid(1, H_ / BAND, B_ * C_);
    blur_kernel<<<grid, dim3(256), 0, stream>>>(x, mask, out);
}

// Round 5
// 408.979 us; speedup vs baseline: 1.3492x; 1.3492x over previous
//
#include <hip/hip_runtime.h>

// HeavySnow: stamp flakes (0.95 squares, all channels) -> depthwise 5x5
// gaussian blur (zero pad) -> clip [0,1].
// R7: R6 structure (barrier-free register sliding window, 4-deep main
// prefetch, BAND=16 for 8 blocks/CU of supply) with the spill fixed:
// __launch_bounds__(256,4) instead of (256,8). R6's (256,8) clamped the
// allocator to 32 VGPRs -> px/acc spilled to scratch (WRITE_SIZE 399 MB vs
// 201 mandatory, +190 MB spill). With a 128-VGPR cap the kernel lands at
// ~52-60 VGPRs (<=64), so hardware occupancy is 8 blocks/CU anyway - earned,
// not forced.

#define H_ 1024
#define W_ 1024
#define B_ 16
#define C_ 3
#define NF_ 15728
#define MASK_WORDS_PER_B (H_ * W_ / 32)  // 32768 words (128 KB) per batch

// Gaussian weights: sigma=1.5, K=5, normalized. g = [g0,g1,g2,g1,g0].
#define G0 0.12007838f
#define G1 0.23388076f
#define G2 0.29208172f

__global__ void clear_mask_kernel(uint4* __restrict__ mask, int n4) {
    int i = blockIdx.x * blockDim.x + threadIdx.x;
    if (i < n4) mask[i] = make_uint4(0u, 0u, 0u, 0u);
}

__global__ void stamp_kernel(const int* __restrict__ ys, const int* __restrict__ xs,
                             const int* __restrict__ rs, unsigned int* __restrict__ mask) {
    int t = blockIdx.x * blockDim.x + threadIdx.x;
    if (t >= B_ * NF_) return;
    int b = t / NF_;
    int y0 = ys[t], x0 = xs[t], r = rs[t];
    unsigned int* mb = mask + b * MASK_WORDS_PER_B;
    int xlo = max(x0 - r, 0), xhi = min(x0 + r, W_ - 1);
    int ylo = max(y0 - r, 0), yhi = min(y0 + r, H_ - 1);
    for (int y = ylo; y <= yhi; ++y) {
        int i0 = (y << 10) + xlo;
        int i1 = (y << 10) + xhi;
        int w0 = i0 >> 5, w1 = i1 >> 5;
        unsigned int m0 = ~0u << (i0 & 31);
        unsigned int m1 = ~0u >> (31 - (i1 & 31));
        if (w0 == w1) {
            atomicOr(mb + w0, m0 & m1);
        } else {
            atomicOr(mb + w0, m0);
            atomicOr(mb + w1, m1);
        }
    }
}

constexpr int BAND = 16;           // output rows per block
constexpr int NITER = BAND + 4;    // raw rows consumed per band

__global__ __launch_bounds__(256, 4) void blur_kernel(const float* __restrict__ x,
                                                      const unsigned int* __restrict__ mask,
                                                      float* __restrict__ out) {
    const int plane = blockIdx.z;          // b*C + c
    const int b = plane / C_;
    const float* xp = x + (size_t)plane * (H_ * W_);
    float* op = out + (size_t)plane * (H_ * W_);
    const unsigned int* mb = mask + b * MASK_WORDS_PER_B;

    const int tid = threadIdx.x;
    const int wv = tid >> 6;               // wave id 0..3 -> strip
    const int ln = tid & 63;               // lane -> float4 word in strip
    const int gx4 = (wv << 8) + (ln << 2); // scalar col of this lane's word
    const int y0 = blockIdx.y * BAND;

    const bool isL = (ln == 0), isR = (ln == 63);
    // Halo float2: L lane needs scalars gx4-2,gx4-1; R lane needs gx4+4,gx4+5.
    const int hoff = isL ? gx4 - 2 : gx4 + 4;
    const bool haloOn = (isL || isR) && ((unsigned)hoff < (unsigned)W_);
    const int mwi = gx4 >> 5, mbit = gx4 & 31;
    const int hwi = hoff >> 5, hbit = hoff & 31;

    float4 acc[5];                         // rotating vertical accumulators
    float2 hacc[5];                        // halo accumulators (lanes 0/63)
    #pragma unroll
    for (int s = 0; s < 5; ++s) {
        acc[s] = make_float4(0.f, 0.f, 0.f, 0.f);
        hacc[s] = make_float2(0.f, 0.f);
    }

    float4 px[4];                          // 4-deep main prefetch (HBM stream)
    unsigned int pm[2];                    // 2-deep mask prefetch (L2-resident)
    float2 ph[2];  unsigned int phm[2];    // 2-deep halo prefetch (L1/L2-resident)
    #pragma unroll
    for (int s = 0; s < 4; ++s) px[s] = make_float4(0.f, 0.f, 0.f, 0.f);
    ph[0] = ph[1] = make_float2(0.f, 0.f);
    pm[0] = pm[1] = 0u; phm[0] = phm[1] = 0u;

    auto load_main = [&](int i, float4& vx) {
        int gy = y0 - 2 + i;
        if ((unsigned)gy < (unsigned)H_) {
            vx = *(const float4*)(xp + (gy << 10) + gx4);
        } else {
            vx = make_float4(0.f, 0.f, 0.f, 0.f);
        }
    };
    auto load_aux = [&](int i, unsigned int& vm, float2& vh, unsigned int& vhm) {
        int gy = y0 - 2 + i;
        if ((unsigned)gy < (unsigned)H_) {
            vm = mb[(gy << 5) + mwi];
            if (haloOn) {
                vh = *(const float2*)(xp + (gy << 10) + hoff);
                vhm = mb[(gy << 5) + hwi];
            } else { vh = make_float2(0.f, 0.f); vhm = 0u; }
        } else {
            vm = 0u; vh = make_float2(0.f, 0.f); vhm = 0u;
        }
    };

    load_main(0, px[0]); load_main(1, px[1]);
    load_main(2, px[2]); load_main(3, px[3]);
    load_aux(0, pm[0], ph[0], phm[0]);
    load_aux(1, pm[1], ph[1], phm[1]);

    #pragma unroll
    for (int i = 0; i < NITER; ++i) {
        // consume pending row (raw row gy = y0-2+i), flake substitution
        float4 vr = px[i & 3];
        unsigned int m = pm[i & 1];
        if ((m >> (mbit + 0)) & 1u) vr.x = 0.95f;
        if ((m >> (mbit + 1)) & 1u) vr.y = 0.95f;
        if ((m >> (mbit + 2)) & 1u) vr.z = 0.95f;
        if ((m >> (mbit + 3)) & 1u) vr.w = 0.95f;
        float2 hr = ph[i & 1];
        unsigned int hm = phm[i & 1];
        if ((hm >> (hbit + 0)) & 1u) hr.x = 0.95f;
        if ((hm >> (hbit + 1)) & 1u) hr.y = 0.95f;

        // refill prefetch slots
        if (i + 4 < NITER) load_main(i + 4, px[i & 3]);
        if (i + 2 < NITER) load_aux(i + 2, pm[i & 1], ph[i & 1], phm[i & 1]);

        // vertical accumulation into up to 5 rotating accumulators
        #pragma unroll
        for (int d = -2; d <= 2; ++d) {
            int ti = i - 2 + d;            // target output row index in band
            if (ti < 0 || ti >= BAND) continue;
            const float wk = (d == -2 || d == 2) ? G0 : ((d == -1 || d == 1) ? G1 : G2);
            const int sl = ti % 5;
            acc[sl].x += wk * vr.x; acc[sl].y += wk * vr.y;
            acc[sl].z += wk * vr.z; acc[sl].w += wk * vr.w;
            hacc[sl].x += wk * hr.x; hacc[sl].y += wk * hr.y;
        }

        // finish output row ti = i-4 (all 5 contributions in)
        if (i >= 4) {
            const int ti = i - 4;
            const int sl = ti % 5;
            float4 vb = acc[sl];
            float2 hvb = hacc[sl];
            float az = __shfl_up(vb.z, 1u);    // v[4l-2] from lane l-1
            float aw = __shfl_up(vb.w, 1u);    // v[4l-1]
            float cx = __shfl_down(vb.x, 1u);  // v[4l+4] from lane l+1
            float cy = __shfl_down(vb.y, 1u);  // v[4l+5]
            az = isL ? hvb.x : az;  aw = isL ? hvb.y : aw;
            cx = isR ? hvb.x : cx;  cy = isR ? hvb.y : cy;
            float4 o;
            o.x = G0 * (az + vb.z) + G1 * (aw + vb.y) + G2 * vb.x;
            o.y = G0 * (aw + vb.w) + G1 * (vb.x + vb.z) + G2 * vb.y;
            o.z = G0 * (vb.x + cx) + G1 * (vb.y + vb.w) + G2 * vb.z;
            o.w = G0 * (vb.y + cy) + G1 * (vb.z + cx) + G2 * vb.w;
            o.x = fminf(fmaxf(o.x, 0.0f), 1.0f);
            o.y = fminf(fmaxf(o.y, 0.0f), 1.0f);
            o.z = fminf(fmaxf(o.z, 0.0f), 1.0f);
            o.w = fminf(fmaxf(o.w, 0.0f), 1.0f);
            *(float4*)(op + ((y0 + ti) << 10) + gx4) = o;
            acc[sl] = make_float4(0.f, 0.f, 0.f, 0.f);
            hacc[sl] = make_float2(0.f, 0.f);
        }
    }
}

extern "C" void kernel_launch(void* const* d_in, const int* in_sizes, int n_in,
                              void* d_out, int out_size, void* d_ws, size_t ws_size,
                              hipStream_t stream) {
    const float* x  = (const float*)d_in[0];
    const int*   ys = (const int*)d_in[1];
    const int*   xs = (const int*)d_in[2];
    const int*   rs = (const int*)d_in[3];
    float* out = (float*)d_out;
    unsigned int* mask = (unsigned int*)d_ws;  // 16 * 32768 words = 2 MB

    int n4 = B_ * MASK_WORDS_PER_B / 4;
    clear_mask_kernel<<<dim3((n4 + 255) / 256), dim3(256), 0, stream>>>((uint4*)mask, n4);

    int nst = B_ * NF_;
    stamp_kernel<<<dim3((nst + 255) / 256), dim3(256), 0, stream>>>(ys, xs, rs, mask);

    dim3 grid(1, H_ / BAND, B_ * C_);
    blur_kernel<<<grid, dim3(256), 0, stream>>>(x, mask, out);
}

// Round 6
// 406.572 us; speedup vs baseline: 1.3572x; 1.0059x over previous
//
#include <hip/hip_runtime.h>

// HeavySnow: stamp flakes (0.95 squares, all channels) -> depthwise 5x5
// gaussian blur (zero pad) -> clip [0,1].
// R8: burst-load / compute / burst-store blur. Theory: all prior variants
// interleaved output stores with prefetch loads; vmcnt retires IN ORDER, so a
// load-wait transitively waits for any older store draining into the ~80%-
// utilized write stream (~1000+cy). Here each lane preloads ALL 12 band rows
// (+masks +edge halo) in one prologue burst -- no store precedes any load in
// program order -- then computes 8 output rows fully in registers and stores
// at the end (nontemporal: out is never re-read; keep L2 for x/mask).
// BAND=8, ~112 VGPR (cap 128 via __launch_bounds__(256,4); R6 lesson: never
// cap below natural need -- spill shows as WRITE_SIZE >> 196608).

#define H_ 1024
#define W_ 1024
#define B_ 16
#define C_ 3
#define NF_ 15728
#define MASK_WORDS_PER_B (H_ * W_ / 32)  // 32768 words (128 KB) per batch

// Gaussian weights: sigma=1.5, K=5, normalized. g = [g0,g1,g2,g1,g0].
#define G0 0.12007838f
#define G1 0.23388076f
#define G2 0.29208172f

typedef float nat_f4 __attribute__((ext_vector_type(4)));

__global__ void clear_mask_kernel(uint4* __restrict__ mask, int n4) {
    int i = blockIdx.x * blockDim.x + threadIdx.x;
    if (i < n4) mask[i] = make_uint4(0u, 0u, 0u, 0u);
}

__global__ void stamp_kernel(const int* __restrict__ ys, const int* __restrict__ xs,
                             const int* __restrict__ rs, unsigned int* __restrict__ mask) {
    int t = blockIdx.x * blockDim.x + threadIdx.x;
    if (t >= B_ * NF_) return;
    int b = t / NF_;
    int y0 = ys[t], x0 = xs[t], r = rs[t];
    unsigned int* mb = mask + b * MASK_WORDS_PER_B;
    int xlo = max(x0 - r, 0), xhi = min(x0 + r, W_ - 1);
    int ylo = max(y0 - r, 0), yhi = min(y0 + r, H_ - 1);
    for (int y = ylo; y <= yhi; ++y) {
        int i0 = (y << 10) + xlo;
        int i1 = (y << 10) + xhi;
        int w0 = i0 >> 5, w1 = i1 >> 5;
        unsigned int m0 = ~0u << (i0 & 31);
        unsigned int m1 = ~0u >> (31 - (i1 & 31));
        if (w0 == w1) {
            atomicOr(mb + w0, m0 & m1);
        } else {
            atomicOr(mb + w0, m0);
            atomicOr(mb + w1, m1);
        }
    }
}

constexpr int BAND = 8;            // output rows per block
constexpr int ROWS = BAND + 4;     // raw rows loaded per band (12)

__global__ __launch_bounds__(256, 4) void blur_kernel(const float* __restrict__ x,
                                                      const unsigned int* __restrict__ mask,
                                                      float* __restrict__ out) {
    const int plane = blockIdx.z;          // b*C + c
    const int b = plane / C_;
    const float* xp = x + (size_t)plane * (H_ * W_);
    float* op = out + (size_t)plane * (H_ * W_);
    const unsigned int* mb = mask + b * MASK_WORDS_PER_B;

    const int tid = threadIdx.x;
    const int wv = tid >> 6;               // wave id 0..3 -> 256-px strip
    const int ln = tid & 63;               // lane -> float4 word in strip
    const int gx4 = (wv << 8) + (ln << 2); // scalar col of this lane's word
    const int y0 = blockIdx.y * BAND;

    const bool isL = (ln == 0), isR = (ln == 63);
    // Halo float2: L lane needs scalars gx4-2,gx4-1; R lane needs gx4+4,gx4+5.
    const int hoff = isL ? gx4 - 2 : gx4 + 4;
    const bool haloOn = (isL || isR) && ((unsigned)hoff < (unsigned)W_);
    const int mwi = gx4 >> 5, mbit = gx4 & 31;
    const int hwi = hoff >> 5, hbit = hoff & 31;

    float4 raw[ROWS];                      // 48 VGPR: all band rows
    float2 hraw[ROWS];                     // 24 VGPR: edge-lane halo
    unsigned int rm[ROWS], hrm[ROWS];      // 24 VGPR: mask words

    // ---- prologue: burst-issue ALL loads; zero stores precede them ----
    #pragma unroll
    for (int r = 0; r < ROWS; ++r) {
        int gy = y0 - 2 + r;
        if ((unsigned)gy < (unsigned)H_) {
            raw[r] = *(const float4*)(xp + (gy << 10) + gx4);
            rm[r]  = mb[(gy << 5) + mwi];
            if (haloOn) {
                hraw[r] = *(const float2*)(xp + (gy << 10) + hoff);
                hrm[r]  = mb[(gy << 5) + hwi];
            } else { hraw[r] = make_float2(0.f, 0.f); hrm[r] = 0u; }
        } else {
            raw[r] = make_float4(0.f, 0.f, 0.f, 0.f); rm[r] = 0u;
            hraw[r] = make_float2(0.f, 0.f); hrm[r] = 0u;
        }
    }

    // ---- flake substitution, all in registers ----
    #pragma unroll
    for (int r = 0; r < ROWS; ++r) {
        unsigned int m = rm[r];
        if ((m >> (mbit + 0)) & 1u) raw[r].x = 0.95f;
        if ((m >> (mbit + 1)) & 1u) raw[r].y = 0.95f;
        if ((m >> (mbit + 2)) & 1u) raw[r].z = 0.95f;
        if ((m >> (mbit + 3)) & 1u) raw[r].w = 0.95f;
        unsigned int hm = hrm[r];
        if ((hm >> (hbit + 0)) & 1u) hraw[r].x = 0.95f;
        if ((hm >> (hbit + 1)) & 1u) hraw[r].y = 0.95f;
    }

    // ---- per output row: vertical 5-tap, shfl halo, horizontal, clip, store ----
    #pragma unroll
    for (int t = 0; t < BAND; ++t) {
        float4 vb;
        vb.x = G0 * (raw[t].x + raw[t + 4].x) + G1 * (raw[t + 1].x + raw[t + 3].x) + G2 * raw[t + 2].x;
        vb.y = G0 * (raw[t].y + raw[t + 4].y) + G1 * (raw[t + 1].y + raw[t + 3].y) + G2 * raw[t + 2].y;
        vb.z = G0 * (raw[t].z + raw[t + 4].z) + G1 * (raw[t + 1].z + raw[t + 3].z) + G2 * raw[t + 2].z;
        vb.w = G0 * (raw[t].w + raw[t + 4].w) + G1 * (raw[t + 1].w + raw[t + 3].w) + G2 * raw[t + 2].w;
        float2 hvb;
        hvb.x = G0 * (hraw[t].x + hraw[t + 4].x) + G1 * (hraw[t + 1].x + hraw[t + 3].x) + G2 * hraw[t + 2].x;
        hvb.y = G0 * (hraw[t].y + hraw[t + 4].y) + G1 * (hraw[t + 1].y + hraw[t + 3].y) + G2 * hraw[t + 2].y;

        float az = __shfl_up(vb.z, 1u);    // v[4l-2] from lane l-1
        float aw = __shfl_up(vb.w, 1u);    // v[4l-1]
        float cx = __shfl_down(vb.x, 1u);  // v[4l+4] from lane l+1
        float cy = __shfl_down(vb.y, 1u);  // v[4l+5]
        az = isL ? hvb.x : az;  aw = isL ? hvb.y : aw;
        cx = isR ? hvb.x : cx;  cy = isR ? hvb.y : cy;

        float4 o;
        o.x = G0 * (az + vb.z) + G1 * (aw + vb.y) + G2 * vb.x;
        o.y = G0 * (aw + vb.w) + G1 * (vb.x + vb.z) + G2 * vb.y;
        o.z = G0 * (vb.x + cx) + G1 * (vb.y + vb.w) + G2 * vb.z;
        o.w = G0 * (vb.y + cy) + G1 * (vb.z + cx) + G2 * vb.w;
        o.x = fminf(fmaxf(o.x, 0.0f), 1.0f);
        o.y = fminf(fmaxf(o.y, 0.0f), 1.0f);
        o.z = fminf(fmaxf(o.z, 0.0f), 1.0f);
        o.w = fminf(fmaxf(o.w, 0.0f), 1.0f);

        nat_f4 ov;
        ov.x = o.x; ov.y = o.y; ov.z = o.z; ov.w = o.w;
        __builtin_nontemporal_store(ov, (nat_f4*)(op + ((y0 + t) << 10) + gx4));
    }
}

extern "C" void kernel_launch(void* const* d_in, const int* in_sizes, int n_in,
                              void* d_out, int out_size, void* d_ws, size_t ws_size,
                              hipStream_t stream) {
    const float* x  = (const float*)d_in[0];
    const int*   ys = (const int*)d_in[1];
    const int*   xs = (const int*)d_in[2];
    const int*   rs = (const int*)d_in[3];
    float* out = (float*)d_out;
    unsigned int* mask = (unsigned int*)d_ws;  // 16 * 32768 words = 2 MB

    int n4 = B_ * MASK_WORDS_PER_B / 4;
    clear_mask_kernel<<<dim3((n4 + 255) / 256), dim3(256), 0, stream>>>((uint4*)mask, n4);

    int nst = B_ * NF_;
    stamp_kernel<<<dim3((nst + 255) / 256), dim3(256), 0, stream>>>(ys, xs, rs, mask);

    dim3 grid(1, H_ / BAND, B_ * C_);
    blur_kernel<<<grid, dim3(256), 0, stream>>>(x, mask, out);
}

// Round 7
// 401.444 us; speedup vs baseline: 1.3745x; 1.0128x over previous
//
#include <hip/hip_runtime.h>

// HeavySnow: stamp flakes (0.95 squares, all channels) -> depthwise 5x5
// gaussian blur (zero pad) -> clip [0,1].
// R9: R8 burst structure with two counter-driven fixes:
//  1) Edge-halo register pipes deleted (-36 wave-wide VGPRs used by 2/64
//     lanes). Vertical filter computed IN PLACE (vb[t] overwrites raw[t]);
//     the 2 wave-edge scalars per row are exchanged via a 512 B LDS buffer
//     with ONE barrier, placed where no VMEM is outstanding (after all loads
//     consumed, before any store). Target VGPR < 64 (R8 sat exactly on the
//     64-VGPR occupancy boundary).
//  2) Bijective XCD swizzle on a 1-D grid (6144 %% 8 == 0): each XCD owns 6
//     whole planes; adjacent y-bands run consecutively on the SAME XCD, so
//     the 4 shared halo rows + mask words are XCD-local L2 hits instead of
//     L3/fabric round-trips (R8: blocks round-robin across XCDs -> zero
//     inter-block L2 reuse, FETCH 149 MB vs ~100 compulsory).

#define H_ 1024
#define W_ 1024
#define B_ 16
#define C_ 3
#define NF_ 15728
#define MASK_WORDS_PER_B (H_ * W_ / 32)  // 32768 words (128 KB) per batch

// Gaussian weights: sigma=1.5, K=5, normalized. g = [g0,g1,g2,g1,g0].
#define G0 0.12007838f
#define G1 0.23388076f
#define G2 0.29208172f

typedef float nat_f4 __attribute__((ext_vector_type(4)));

__global__ void clear_mask_kernel(uint4* __restrict__ mask, int n4) {
    int i = blockIdx.x * blockDim.x + threadIdx.x;
    if (i < n4) mask[i] = make_uint4(0u, 0u, 0u, 0u);
}

__global__ void stamp_kernel(const int* __restrict__ ys, const int* __restrict__ xs,
                             const int* __restrict__ rs, unsigned int* __restrict__ mask) {
    int t = blockIdx.x * blockDim.x + threadIdx.x;
    if (t >= B_ * NF_) return;
    int b = t / NF_;
    int y0 = ys[t], x0 = xs[t], r = rs[t];
    unsigned int* mb = mask + b * MASK_WORDS_PER_B;
    int xlo = max(x0 - r, 0), xhi = min(x0 + r, W_ - 1);
    int ylo = max(y0 - r, 0), yhi = min(y0 + r, H_ - 1);
    for (int y = ylo; y <= yhi; ++y) {
        int i0 = (y << 10) + xlo;
        int i1 = (y << 10) + xhi;
        int w0 = i0 >> 5, w1 = i1 >> 5;
        unsigned int m0 = ~0u << (i0 & 31);
        unsigned int m1 = ~0u >> (31 - (i1 & 31));
        if (w0 == w1) {
            atomicOr(mb + w0, m0 & m1);
        } else {
            atomicOr(mb + w0, m0);
            atomicOr(mb + w1, m1);
        }
    }
}

constexpr int BAND = 8;            // output rows per block
constexpr int ROWS = BAND + 4;     // raw rows loaded per band (12)
constexpr int NYB = H_ / BAND;     // 128 y-bands per plane
constexpr int NWG = NYB * B_ * C_; // 6144 workgroups (divisible by 8)

__global__ __launch_bounds__(256, 4) void blur_kernel(const float* __restrict__ x,
                                                      const unsigned int* __restrict__ mask,
                                                      float* __restrict__ out) {
    // ---- bijective XCD swizzle: each XCD gets a contiguous chunk of 768
    //      blocks = 6 complete planes, y-bands in order ----
    const int bid = blockIdx.x;
    const int swz = (bid & 7) * (NWG / 8) + (bid >> 3);
    const int plane = swz >> 7;            // /128  -> b*C + c
    const int yband = swz & 127;

    const int b = plane / C_;
    const float* xp = x + (size_t)plane * (H_ * W_);
    float* op = out + (size_t)plane * (H_ * W_);
    const unsigned int* mb = mask + b * MASK_WORDS_PER_B;

    const int tid = threadIdx.x;
    const int wv = tid >> 6;               // wave id 0..3 -> 256-px strip
    const int ln = tid & 63;               // lane -> float4 word in strip
    const int gx4 = (wv << 8) + (ln << 2); // scalar col of this lane's word
    const int y0 = yband * BAND;

    const bool isL = (ln == 0), isR = (ln == 63);
    const int mwi = gx4 >> 5, mbit = gx4 & 31;

    float4 raw[ROWS];                      // 48 VGPR: all band rows
    unsigned int rm[ROWS];                 // mask words (short-lived)

    // wave-edge v-filtered scalars: edges[wave][row][0]=lane0 (x,y),
    // edges[wave][row][1]=lane63 (z,w). 512 B.
    __shared__ float2 edges[4][BAND][2];

    // ---- burst-issue ALL loads; no stores precede them ----
    #pragma unroll
    for (int r = 0; r < ROWS; ++r) {
        int gy = y0 - 2 + r;
        if ((unsigned)gy < (unsigned)H_) {
            raw[r] = *(const float4*)(xp + (gy << 10) + gx4);
            rm[r]  = mb[(gy << 5) + mwi];
        } else {
            raw[r] = make_float4(0.f, 0.f, 0.f, 0.f); rm[r] = 0u;
        }
    }

    // ---- flake substitution, in registers ----
    #pragma unroll
    for (int r = 0; r < ROWS; ++r) {
        unsigned int m = rm[r];
        if ((m >> (mbit + 0)) & 1u) raw[r].x = 0.95f;
        if ((m >> (mbit + 1)) & 1u) raw[r].y = 0.95f;
        if ((m >> (mbit + 2)) & 1u) raw[r].z = 0.95f;
        if ((m >> (mbit + 3)) & 1u) raw[r].w = 0.95f;
    }

    // ---- vertical 5-tap IN PLACE: raw[t] <- vb[t] (raw[t] dead after) ----
    #pragma unroll
    for (int t = 0; t < BAND; ++t) {
        float4 vb;
        vb.x = G0 * (raw[t].x + raw[t + 4].x) + G1 * (raw[t + 1].x + raw[t + 3].x) + G2 * raw[t + 2].x;
        vb.y = G0 * (raw[t].y + raw[t + 4].y) + G1 * (raw[t + 1].y + raw[t + 3].y) + G2 * raw[t + 2].y;
        vb.z = G0 * (raw[t].z + raw[t + 4].z) + G1 * (raw[t + 1].z + raw[t + 3].z) + G2 * raw[t + 2].z;
        vb.w = G0 * (raw[t].w + raw[t + 4].w) + G1 * (raw[t + 1].w + raw[t + 3].w) + G2 * raw[t + 2].w;
        if (isL) edges[wv][t][0] = make_float2(vb.x, vb.y);
        if (isR) edges[wv][t][1] = make_float2(vb.z, vb.w);
        raw[t] = vb;
    }
    __syncthreads();   // only LDS writes outstanding; loads consumed, no stores yet

    // ---- per row: shfl + LDS edge halo, horizontal 5-tap, clip, store ----
    #pragma unroll
    for (int t = 0; t < BAND; ++t) {
        float4 vb = raw[t];
        float az = __shfl_up(vb.z, 1u);    // v[4l-2] from lane l-1
        float aw = __shfl_up(vb.w, 1u);    // v[4l-1]
        float cx = __shfl_down(vb.x, 1u);  // v[4l+4] from lane l+1
        float cy = __shfl_down(vb.y, 1u);  // v[4l+5]
        if (isL) {
            if (wv > 0) { float2 e = edges[wv - 1][t][1]; az = e.x; aw = e.y; }
            else        { az = 0.f; aw = 0.f; }            // zero-pad at x<0
        }
        if (isR) {
            if (wv < 3) { float2 e = edges[wv + 1][t][0]; cx = e.x; cy = e.y; }
            else        { cx = 0.f; cy = 0.f; }            // zero-pad at x>=W
        }
        float4 o;
        o.x = G0 * (az + vb.z) + G1 * (aw + vb.y) + G2 * vb.x;
        o.y = G0 * (aw + vb.w) + G1 * (vb.x + vb.z) + G2 * vb.y;
        o.z = G0 * (vb.x + cx) + G1 * (vb.y + vb.w) + G2 * vb.z;
        o.w = G0 * (vb.y + cy) + G1 * (vb.z + cx) + G2 * vb.w;
        o.x = fminf(fmaxf(o.x, 0.0f), 1.0f);
        o.y = fminf(fmaxf(o.y, 0.0f), 1.0f);
        o.z = fminf(fmaxf(o.z, 0.0f), 1.0f);
        o.w = fminf(fmaxf(o.w, 0.0f), 1.0f);

        nat_f4 ov;
        ov.x = o.x; ov.y = o.y; ov.z = o.z; ov.w = o.w;
        __builtin_nontemporal_store(ov, (nat_f4*)(op + ((y0 + t) << 10) + gx4));
    }
}

extern "C" void kernel_launch(void* const* d_in, const int* in_sizes, int n_in,
                              void* d_out, int out_size, void* d_ws, size_t ws_size,
                              hipStream_t stream) {
    const float* x  = (const float*)d_in[0];
    const int*   ys = (const int*)d_in[1];
    const int*   xs = (const int*)d_in[2];
    const int*   rs = (const int*)d_in[3];
    float* out = (float*)d_out;
    unsigned int* mask = (unsigned int*)d_ws;  // 16 * 32768 words = 2 MB

    int n4 = B_ * MASK_WORDS_PER_B / 4;
    clear_mask_kernel<<<dim3((n4 + 255) / 256), dim3(256), 0, stream>>>((uint4*)mask, n4);

    int nst = B_ * NF_;
    stamp_kernel<<<dim3((nst + 255) / 256), dim3(256), 0, stream>>>(ys, xs, rs, mask);

    blur_kernel<<<dim3(NWG), dim3(256), 0, stream>>>(x, mask, out);
}